// Round 2
// baseline (181.321 us; speedup 1.0000x reference)
//
#include <hip/hip_runtime.h>
#include <hip/hip_cooperative_groups.h>

namespace cg = cooperative_groups;

#define SIGMA 0.1f
#define RHO   10.0f
#define B     8
#define F     64
#define ROWS_PER_BLOCK 4
#define NBLOCKS ((B * B * F) / ROWS_PER_BLOCK)   // 1024

// R2: single cooperative kernel = row phase + grid sync + finish phase.
// 1024 blocks x 256 threads (4 waves/block -> co-residency needs 4 blocks/CU,
// capacity is 8 blocks/CU at 256 thr & low VGPR -> cooperative launch OK).
// Row phase identical to the R0 (measured-best) branchy kernel; the only
// structural change vs R0 is the fusion of finish_kernel via grid.sync(),
// removing one dispatch + the inter-kernel serialization gap.
__global__ __launch_bounds__(256) void fused_kernel(
    const float* __restrict__ sim,
    const float* __restrict__ pos,
    const float* __restrict__ neg,
    const float* __restrict__ label,
    float* __restrict__ partial,   // [1024] in d_ws
    float* __restrict__ out)       // scalar
{
    const int lane = threadIdx.x & 63;
    const int w    = threadIdx.x >> 6;
    const int row  = blockIdx.x * ROWS_PER_BLOCK + w;
    const int pair = row >> 6;               // row / F

    __shared__ float ls[ROWS_PER_BLOCK][F];
    __shared__ float psum[ROWS_PER_BLOCK];

    const size_t base = (size_t)row * F;
    const float sj = sim[base + lane];
    const float pj = pos[base + lane];
    const float nj = neg[base + lane];
    ls[w][lane] = sj;                        // wave-synchronous; no barrier needed

    // wave-uniform 64-bit predicate masks
    const unsigned long long pmask = __ballot(pj > 0.5f);
    const unsigned long long nonly = __ballot(nj > 0.5f) & ~pmask;

    float all_acc = 0.0f;
    float pos_acc = 0.0f;

    for (int k = 0; k < F; ++k) {
        if ((pmask >> k) & 1ull) {
            // pos_pos path: rho * heaviside(d); d==0 at k==lane self-zeroes
            const float d = ls[w][k] - sj;
            const float v = (d > 0.0f) ? RHO : 0.0f;
            all_acc += v;
            pos_acc += v;
        } else if ((nonly >> k) & 1ull) {
            // pos_neg path: quad_linear(d). k==lane here implies pj==0, whose
            // term is annihilated below, so no diagonal masking needed.
            const float d  = ls[w][k] - sj;
            const float xs = d * (1.0f / SIGMA);
            const float t  = xs + 1.0f;
            const float v  = (d > 0.0f) ? fmaf(2.0f, xs, 1.0f)
                                        : ((t >= 0.0f) ? t * t : 0.0f);
            all_acc += v;
        }
        // neither pos nor neg: contributes 0, skip
    }

    const float all_rk = all_acc + 1.0f;     // >= 1, no div hazard
    const float pos_rk = pos_acc + 1.0f;

    float term = (pj > 0.5f) ? (pos_rk / all_rk) : 0.0f;
    float cntv = (pj > 0.5f) ? 1.0f : 0.0f;

    #pragma unroll
    for (int off = 32; off > 0; off >>= 1) {
        term += __shfl_down(term, off, 64);
        cntv += __shfl_down(cntv, off, 64);
    }

    if (lane == 0) psum[w] = term / cntv;    // this row's pos_divide/pos_cnt
    __syncthreads();

    if (threadIdx.x == 0) {
        const float lab = label[pair];
        const float s = psum[0] + psum[1] + psum[2] + psum[3];
        partial[blockIdx.x] = s * (1.0f / F) * lab;
    }

    // Make the partial visible device-wide, then grid-wide barrier.
    __threadfence();
    cg::this_grid().sync();

    // ---- finish phase: block 0 only ----
    if (blockIdx.x == 0) {
        const int t = threadIdx.x;

        const float4 v = ((const float4*)partial)[t];   // coalesced, 16 B/lane
        float s = v.x + v.y + v.z + v.w;
        #pragma unroll
        for (int off = 32; off > 0; off >>= 1) s += __shfl_down(s, off, 64);

        __shared__ float sm[4];
        if (lane == 0) sm[w] = s;
        __syncthreads();

        if (t < 64) {
            float den = label[t];
            #pragma unroll
            for (int off = 32; off > 0; off >>= 1) den += __shfl_down(den, off, 64);
            if (t == 0) {
                const float num = sm[0] + sm[1] + sm[2] + sm[3];
                out[0] = 1.0f - num / den;
            }
        }
    }
}

extern "C" void kernel_launch(void* const* d_in, const int* in_sizes, int n_in,
                              void* d_out, int out_size, void* d_ws, size_t ws_size,
                              hipStream_t stream)
{
    const float* sim   = (const float*)d_in[0];  // [B,B,F,F]
    const float* pos   = (const float*)d_in[1];  // [B,B,F,F]
    const float* neg   = (const float*)d_in[2];  // [B,B,F,F]
    const float* label = (const float*)d_in[3];  // [B,B]
    float*       out   = (float*)d_out;          // scalar
    float*       part  = (float*)d_ws;           // [1024] partials

    void* args[] = { (void*)&sim, (void*)&pos, (void*)&neg, (void*)&label,
                     (void*)&part, (void*)&out };
    hipLaunchCooperativeKernel(reinterpret_cast<void*>(fused_kernel),
                               dim3(NBLOCKS), dim3(256), args, 0, stream);
}

// Round 4
// 67.962 us; speedup vs baseline: 2.6680x; 2.6680x over previous
//
#include <hip/hip_runtime.h>

#define SIGMA 0.1f
#define RHO   10.0f
#define B     8
#define F     64
#define ROWS_PER_BLOCK 4

// R4 = resubmit of R3 (GPU acquisition timed out; no measurement taken).
// R3 = exact revert to R0 (best measured: 69.3 us end-to-end).
// 1024 blocks x 256 threads; wave w handles row = blockIdx*4 + w.
// All 4 rows of a block belong to the same (b1,b2) pair (4 | 64).
// Emits per-block partial of:  sum_rows (pos_divide/pos_cnt) * (1/F) * label[pair]
//
// Session findings (R1/R2): end-to-end time is dominated by a fixed ~40 us
// harness workspace-poison fill + ~20 us graph overhead; row_kernel is ~5 us.
// Branchless/unrolled loop (R1): neutral-to-noise. Cooperative fusion (R2):
// grid.sync() over 1024 blocks costs ~100 us -> 2.5x regression. Two plain
// dispatches is the measured-best structure.
__global__ __launch_bounds__(256) void row_kernel(
    const float* __restrict__ sim,
    const float* __restrict__ pos,
    const float* __restrict__ neg,
    const float* __restrict__ label,
    float* __restrict__ partial)   // [1024]
{
    const int lane = threadIdx.x & 63;
    const int w    = threadIdx.x >> 6;
    const int row  = blockIdx.x * ROWS_PER_BLOCK + w;
    const int pair = row >> 6;               // row / F

    __shared__ float ls[ROWS_PER_BLOCK][F];
    __shared__ float psum[ROWS_PER_BLOCK];

    const size_t base = (size_t)row * F;
    const float sj = sim[base + lane];
    const float pj = pos[base + lane];
    const float nj = neg[base + lane];
    ls[w][lane] = sj;                        // wave-synchronous; no barrier needed

    // wave-uniform 64-bit predicate masks
    const unsigned long long pmask = __ballot(pj > 0.5f);
    const unsigned long long nonly = __ballot(nj > 0.5f) & ~pmask;

    float all_acc = 0.0f;
    float pos_acc = 0.0f;

    for (int k = 0; k < F; ++k) {
        if ((pmask >> k) & 1ull) {
            // pos_pos path: rho * heaviside(d); d==0 at k==lane self-zeroes
            const float d = ls[w][k] - sj;
            const float v = (d > 0.0f) ? RHO : 0.0f;
            all_acc += v;
            pos_acc += v;
        } else if ((nonly >> k) & 1ull) {
            // pos_neg path: quad_linear(d). k==lane here implies pj==0, whose
            // term is annihilated below, so no diagonal masking needed.
            const float d  = ls[w][k] - sj;
            const float xs = d * (1.0f / SIGMA);
            const float t  = xs + 1.0f;
            const float v  = (d > 0.0f) ? fmaf(2.0f, xs, 1.0f)
                                        : ((t >= 0.0f) ? t * t : 0.0f);
            all_acc += v;
        }
        // neither pos nor neg: contributes 0, skip
    }

    const float all_rk = all_acc + 1.0f;     // >= 1, no div hazard
    const float pos_rk = pos_acc + 1.0f;

    float term = (pj > 0.5f) ? (pos_rk / all_rk) : 0.0f;
    float cntv = (pj > 0.5f) ? 1.0f : 0.0f;

    #pragma unroll
    for (int off = 32; off > 0; off >>= 1) {
        term += __shfl_down(term, off, 64);
        cntv += __shfl_down(cntv, off, 64);
    }

    if (lane == 0) psum[w] = term / cntv;    // this row's pos_divide/pos_cnt
    __syncthreads();

    if (threadIdx.x == 0) {
        const float lab = label[pair];
        const float s = psum[0] + psum[1] + psum[2] + psum[3];
        partial[blockIdx.x] = s * (1.0f / F) * lab;
    }
}

// 1 block x 256 threads: num = sum(partial[0..1023]); den = sum(label[0..63]);
// out = 1 - num/den
__global__ __launch_bounds__(256) void finish_kernel(
    const float* __restrict__ partial,
    const float* __restrict__ label,
    float* __restrict__ out)
{
    const int t    = threadIdx.x;
    const int lane = t & 63;
    const int w    = t >> 6;

    const float4 v = ((const float4*)partial)[t];   // coalesced, 16 B/lane
    float s = v.x + v.y + v.z + v.w;
    #pragma unroll
    for (int off = 32; off > 0; off >>= 1) s += __shfl_down(s, off, 64);

    __shared__ float sm[4];
    if (lane == 0) sm[w] = s;
    __syncthreads();

    if (t < 64) {
        float den = label[t];
        #pragma unroll
        for (int off = 32; off > 0; off >>= 1) den += __shfl_down(den, off, 64);
        if (t == 0) {
            const float num = sm[0] + sm[1] + sm[2] + sm[3];
            out[0] = 1.0f - num / den;
        }
    }
}

extern "C" void kernel_launch(void* const* d_in, const int* in_sizes, int n_in,
                              void* d_out, int out_size, void* d_ws, size_t ws_size,
                              hipStream_t stream)
{
    const float* sim   = (const float*)d_in[0];  // [B,B,F,F]
    const float* pos   = (const float*)d_in[1];  // [B,B,F,F]
    const float* neg   = (const float*)d_in[2];  // [B,B,F,F]
    const float* label = (const float*)d_in[3];  // [B,B]
    float*       out   = (float*)d_out;          // scalar
    float*       part  = (float*)d_ws;           // [1024] partials

    row_kernel<<<(B * B * F) / ROWS_PER_BLOCK, 256, 0, stream>>>(sim, pos, neg, label, part);
    finish_kernel<<<1, 256, 0, stream>>>(part, label, out);
}